// Round 3
// baseline (3915.458 us; speedup 1.0000x reference)
//
#include <hip/hip_runtime.h>
#include <stdint.h>

// B=256, S=512, ENC=256, DEC=256, ATTN=128, H=48
#define LOG2E 1.4426950408889634f
#define SCOPE __HIP_MEMORY_SCOPE_AGENT

typedef short v8s __attribute__((ext_vector_type(8)));
typedef float v4f __attribute__((ext_vector_type(4)));

__device__ __forceinline__ uint32_t bf16r(float x){
  uint32_t u = __float_as_uint(x);
  return (u + 0x7fffu + ((u >> 16) & 1u)) >> 16;   // RNE round to bf16
}
__device__ __forceinline__ uint32_t pack2(float lo, float hi){
  return bf16r(lo) | (bf16r(hi) << 16);
}
__device__ __forceinline__ float unlo(uint32_t u){ return __uint_as_float(u << 16); }
__device__ __forceinline__ float unhi(uint32_t u){ return __uint_as_float(u & 0xffff0000u); }

__device__ __forceinline__ float fexp2(float x){ return __builtin_amdgcn_exp2f(x); }
__device__ __forceinline__ float frcp(float x){ return __builtin_amdgcn_rcpf(x); }
__device__ __forceinline__ float ftanh(float x){
  float e = fexp2(x * (2.0f * LOG2E));   // exp(2x)
  return 1.0f - 2.0f * frcp(e + 1.0f);
}
__device__ __forceinline__ float fsig(float x){
  return frcp(1.0f + fexp2(-x * LOG2E));
}
__device__ __forceinline__ float wave_sum(float x){
  #pragma unroll
  for(int o = 32; o; o >>= 1) x += __shfl_xor(x, o, 64);
  return x;
}

// Coherent (agent-scope, L3-serialized) access helpers.
__device__ __forceinline__ unsigned flag_ld(const unsigned* p){
  return __hip_atomic_load(p, __ATOMIC_RELAXED, SCOPE);
}
__device__ __forceinline__ void flag_st(unsigned* p, unsigned v){
  __hip_atomic_store(p, v, __ATOMIC_RELAXED, SCOPE);
}
__device__ __forceinline__ float ldf_c(const float* p){
  return __hip_atomic_load(p, __ATOMIC_RELAXED, SCOPE);
}
__device__ __forceinline__ void stf_c(float* p, float v){
  __hip_atomic_store(p, v, __ATOMIC_RELAXED, SCOPE);
}
__device__ __forceinline__ uint64_t ld64_c(const uint64_t* p){
  return __hip_atomic_load(p, __ATOMIC_RELAXED, SCOPE);
}
__device__ __forceinline__ void st64_c(uint64_t* p, uint64_t v){
  __hip_atomic_store(p, v, __ATOMIC_RELAXED, SCOPE);
}
__device__ __forceinline__ void st32_c(uint32_t* p, uint32_t v){
  __hip_atomic_store(p, v, __ATOMIC_RELAXED, SCOPE);
}
__device__ __forceinline__ void st16_c(unsigned short* p, unsigned short v){
  __hip_atomic_store(p, v, __ATOMIC_RELAXED, SCOPE);
}

// Gate-row interleave: jg = n*64 + dl*4 + gate ; row = gate*256 + n*16 + dl
__device__ __forceinline__ int gate_row(int jg){
  return (jg & 3) * 256 + (jg >> 6) * 16 + ((jg >> 2) & 15);
}

// ---- P1: pack gate weights bf16 (interleaved rows) + WencT split hi/lo bf16 ----
__global__ __launch_bounds__(256) void k_pack(const float* __restrict__ W_ih,
                                              const float* __restrict__ W_hh,
                                              const float* __restrict__ b_ih,
                                              const float* __restrict__ b_hh,
                                              const float* __restrict__ W_enc,
                                              unsigned short* __restrict__ WmT,
                                              float* __restrict__ biasc,
                                              float* __restrict__ w0v,
                                              unsigned short* __restrict__ WencTh,
                                              unsigned short* __restrict__ WencTl){
  int gid = blockIdx.x * 256 + threadIdx.x;   // 98304
  if(gid < 65536){
    int jg = gid >> 6, k8 = gid & 63;
    int row = gate_row(jg);
    int k0 = k8 * 8;
    uint32_t p[4];
    #pragma unroll
    for(int mm = 0; mm < 4; ++mm){
      int ka = k0 + 2 * mm, kb = ka + 1;
      float lo = (ka < 256) ? W_ih[row * 257 + 1 + ka] : W_hh[row * 256 + (ka - 256)];
      float hi = (kb < 256) ? W_ih[row * 257 + 1 + kb] : W_hh[row * 256 + (kb - 256)];
      p[mm] = pack2(lo, hi);
    }
    *(uint4*)&WmT[(size_t)jg * 512 + k0] = make_uint4(p[0], p[1], p[2], p[3]);
    if(k8 == 0){
      biasc[jg] = b_ih[row] + b_hh[row];
      w0v[jg] = W_ih[row * 257];
    }
  } else {
    int g2 = gid - 65536;                    // 32768 = 256k x 128a
    int k = g2 >> 7, a = g2 & 127;
    float x = W_enc[k * 128 + a];
    uint32_t hb = bf16r(x);
    WencTh[a * 256 + k] = (unsigned short)hb;
    float hv = __uint_as_float(hb << 16);
    WencTl[a * 256 + k] = (unsigned short)bf16r(x - hv);
  }
}

// ---- P2: enc_proj via MFMA bf16 with split hi/lo inputs (near-fp32 precision). ----
__global__ __launch_bounds__(256, 2) void k_enc_proj(const float* __restrict__ enc,
                                                     const unsigned short* __restrict__ WencTh,
                                                     const unsigned short* __restrict__ WencTl,
                                                     unsigned short* __restrict__ ep,
                                                     uint32_t* __restrict__ encb){
  __shared__ unsigned short Ash[128][48];  // [s-local][k-chunk] hi
  __shared__ unsigned short Asl[128][48];  // lo
  __shared__ unsigned short Wth[128][48];  // [a][k-chunk] hi
  __shared__ unsigned short Wtl[128][48];  // lo
  const int tid = threadIdx.x;
  const int b = blockIdx.x >> 2, mt = blockIdx.x & 3;
  const int lane = tid & 63, w = tid >> 6;
  const int rr = lane & 15, quad = lane >> 4;

  v4f acc[2][8];
  #pragma unroll
  for(int g = 0; g < 2; ++g)
    #pragma unroll
    for(int nt = 0; nt < 8; ++nt) acc[g][nt] = (v4f){0.f, 0.f, 0.f, 0.f};

  const float* encBase = enc + ((size_t)(b * 512 + mt * 128)) * 256;
  uint32_t* encbBase = encb + ((size_t)(b * 512 + mt * 128)) * 128;

  for(int kt = 0; kt < 8; ++kt){
    __syncthreads();
    #pragma unroll
    for(int i = 0; i < 4; ++i){
      int flat = i * 256 + tid;              // 1024 = 128 rows x 8 float4
      int row = flat >> 3, c4 = flat & 7;
      float4 f = *(const float4*)(encBase + (size_t)row * 256 + kt * 32 + c4 * 4);
      uint32_t hx = bf16r(f.x), hy = bf16r(f.y), hz = bf16r(f.z), hw = bf16r(f.w);
      uint2 hp = make_uint2(hx | (hy << 16), hz | (hw << 16));
      float lx = f.x - __uint_as_float(hx << 16);
      float ly = f.y - __uint_as_float(hy << 16);
      float lz = f.z - __uint_as_float(hz << 16);
      float lw = f.w - __uint_as_float(hw << 16);
      uint2 lp = make_uint2(pack2(lx, ly), pack2(lz, lw));
      *(uint2*)&Ash[row][c4 * 4] = hp;
      *(uint2*)&Asl[row][c4 * 4] = lp;
      *(uint2*)&encbBase[(size_t)row * 128 + kt * 16 + c4 * 2] = hp;
    }
    #pragma unroll
    for(int i = 0; i < 2; ++i){
      int flat = i * 256 + tid;              // 512 = 128 a x 4 uint4
      int a = flat >> 2, q4 = flat & 3;
      *(uint4*)&Wth[a][q4 * 8] = *(const uint4*)(WencTh + (size_t)a * 256 + kt * 32 + q4 * 8);
      *(uint4*)&Wtl[a][q4 * 8] = *(const uint4*)(WencTl + (size_t)a * 256 + kt * 32 + q4 * 8);
    }
    __syncthreads();
    #pragma unroll
    for(int g = 0; g < 2; ++g){
      v8s ah = *(const v8s*)&Ash[32 * w + 16 * g + rr][quad * 8];
      v8s al = *(const v8s*)&Asl[32 * w + 16 * g + rr][quad * 8];
      #pragma unroll
      for(int nt = 0; nt < 8; ++nt){
        v8s bh = *(const v8s*)&Wth[nt * 16 + rr][quad * 8];
        v8s bl = *(const v8s*)&Wtl[nt * 16 + rr][quad * 8];
        acc[g][nt] = __builtin_amdgcn_mfma_f32_16x16x32_bf16(ah, bh, acc[g][nt], 0, 0, 0);
        acc[g][nt] = __builtin_amdgcn_mfma_f32_16x16x32_bf16(al, bh, acc[g][nt], 0, 0, 0);
        acc[g][nt] = __builtin_amdgcn_mfma_f32_16x16x32_bf16(ah, bl, acc[g][nt], 0, 0, 0);
      }
    }
  }
  #pragma unroll
  for(int g = 0; g < 2; ++g){
    int s0 = 128 * mt + 32 * w + 16 * g + quad * 4;
    #pragma unroll
    for(int nt = 0; nt < 8; ++nt){
      int a = nt * 16 + rr;
      uint2 pp = make_uint2(pack2(acc[g][nt][0], acc[g][nt][1]),
                            pack2(acc[g][nt][2], acc[g][nt][3]));
      *(uint2*)&ep[((size_t)b * 128 + a) * 512 + s0] = pp;
    }
  }
}

// ---- P3: reset flags (ws persists across harness iterations) ----
__global__ __launch_bounds__(512) void k_zero(unsigned* __restrict__ fl){
  fl[threadIdx.x] = 0u;   // flagA[256] | flagB[256]
}

// ---- Persistent fused decoder (round-2 structure + latency/overlap package):
// ep prefetched across the flagB rendezvous; gates h-half MFMA runs inside
// phase A (matrix pipe overlaps scores' trans pipe); context stream register
// double-buffered; conflict-free LDS layouts; fewer barriers.
__global__ __launch_bounds__(512, 2) void k_steps(
    const uint32_t* __restrict__ encb, const unsigned short* __restrict__ ep,
    const unsigned short* __restrict__ WmT, const float* __restrict__ biasc,
    const float* __restrict__ w0v, const float* __restrict__ Wdec,
    const float* __restrict__ Wout, const float* __restrict__ h0,
    const float* __restrict__ c0, const float* __restrict__ v,
    const float* __restrict__ b_out, unsigned* __restrict__ flagA,
    unsigned* __restrict__ flagB, float* __restrict__ predf,
    float* __restrict__ dpp, float* __restrict__ predp,
    unsigned short* __restrict__ xcat2, float* __restrict__ out)
{
  __shared__ __align__(16) unsigned short WT[64][520];  // gate weights (persistent)
  __shared__ __align__(16) unsigned short AT[16][520];  // x rows: [0,256)=ctx [256,512)=h
  __shared__ float WdecL[16][128];                      // Wdec slice (persistent)
  __shared__ float gact[64][20];
  __shared__ float dpf[128];
  __shared__ float vl[128];
  __shared__ float scp[512][10];                        // padded: 2-way max
  __shared__ float attn_l[512];
  __shared__ float ctxp[16][8][33];                     // [g][j][e4] conflict-free
  __shared__ float red2[8];
  __shared__ float hf[256];
  __shared__ float dppart[4][128];
  __shared__ float biasL[64], w0L[64], WoutL[16], predfL[16];
  __shared__ float sB;

  const int tid = threadIdx.x, b = blockIdx.x;
  const int lane = tid & 63, wid = tid >> 6;
  const int m16 = (b >> 4) << 4;     // first batch of our m-group
  const int n = b & 15;              // our gates n-slice

  // ---- one-time staging ----
  {
    const uint4* src = (const uint4*)(WmT + (size_t)(n * 64) * 512);
    #pragma unroll
    for(int i = 0; i < 8; ++i){
      int flat = i * 512 + tid;            // 4096 = 64 rows x 64 uint4
      int r = flat >> 6, q = flat & 63;
      *(uint4*)&WT[r][q * 8] = src[r * 64 + q];
    }
    const float4* wsrc = (const float4*)(Wdec + (size_t)(n * 16) * 128);
    int r2 = tid >> 5, q2 = tid & 31;      // 512 = 16 rows x 32 float4
    *(float4*)&WdecL[r2][q2 * 4] = wsrc[r2 * 32 + q2];
    if(tid < 64){ biasL[tid] = biasc[n * 64 + tid]; w0L[tid] = w0v[n * 64 + tid]; }
    if(tid < 16) WoutL[tid] = Wout[n * 16 + tid];
    if(tid < 128) vl[tid] = v[tid];
    if(tid == 0){ sB = b_out[0]; stf_c(&predf[b], 0.f); }
    // stage AT h-half from h0 directly (t=0 gates input; no cross-block dep)
    #pragma unroll
    for(int i = 0; i < 8; ++i){
      int flat = i * 512 + tid;            // 4096 = 16 r x 256 c
      int r = flat >> 8, c = flat & 255;
      AT[r][256 + c] = (unsigned short)bf16r(h0[(size_t)(m16 + r) * 256 + c]);
    }
  }
  float c_reg = 0.f;
  if(tid < 256){
    int bl = tid >> 4, dl = tid & 15;
    c_reg = c0[(size_t)(m16 + bl) * 256 + n * 16 + dl];
    hf[tid] = h0[(size_t)b * 256 + tid];
  }
  __syncthreads();
  // dpf(t=0) = h0 @ Wdec (f32)
  {
    int a = tid & 127, p = tid >> 7;
    float s = 0.f;
    const float* wd = Wdec + (size_t)(p * 64) * 128 + a;
    #pragma unroll 8
    for(int d = 0; d < 64; ++d) s += hf[p * 64 + d] * wd[(size_t)d * 128];
    dppart[p][a] = s;
  }
  __syncthreads();
  if(tid < 128) dpf[tid] = dppart[0][tid] + dppart[1][tid] + dppart[2][tid] + dppart[3][tid];
  __syncthreads();

  const uint4* ep4 = (const uint4*)(ep + (size_t)b * 65536);
  const uint4* eb  = (const uint4*)(encb + (size_t)b * 65536);

  #pragma unroll 1
  for(int t = 0; t < 48; ++t){
    unsigned short* xcatP = xcat2 + (size_t)(t & 1) * 131072;        // x_t
    unsigned short* xcatN = xcat2 + (size_t)((t + 1) & 1) * 131072;  // h_{t+1} dest

    // ---- ep prefetch (no deps): in flight across rendezvous + folds ----
    uint4 u[16];
    #pragma unroll
    for(int i = 0; i < 16; ++i) u[i] = ep4[(wid * 16 + i) * 64 + lane];

    // ---- A: wait gates(t-1); restage AT h-half; fold dpp/predp ----
    if(t > 0){
      if(tid < 16){
        unsigned want = (unsigned)t;
        while(flag_ld(&flagB[m16 + tid]) < want) __builtin_amdgcn_s_sleep(1);
      }
      __syncthreads();
      {
        const uint64_t* hsrc = (const uint64_t*)(xcatP + (size_t)m16 * 512);
        #pragma unroll
        for(int i = 0; i < 2; ++i){
          int flat = i * 512 + tid;        // 1024 = 16 rows x 64 u64 (h half)
          int r = flat >> 6, q = flat & 63;
          *(uint64_t*)&AT[r][256 + q * 4] = ld64_c(hsrc + (size_t)r * 128 + 64 + q);
        }
      }
      if(tid < 128){
        float s = 0.f;
        #pragma unroll
        for(int nn = 0; nn < 16; ++nn) s += ldf_c(&dpp[((size_t)b * 16 + nn) * 128 + tid]);
        dpf[tid] = s;
      } else if(tid == 128){
        float pf = 0.f;
        #pragma unroll
        for(int nn = 0; nn < 16; ++nn) pf += ldf_c(&predp[nn * 256 + b]);
        pf += sB;
        out[b * 48 + (t - 1)] = pf;
        stf_c(&predf[b], pf);
      }
      __syncthreads();
    }

    // ---- gates GEMV h-half (kt 8..15): matrix pipe, overlaps scores below ----
    v4f acc = {0.f, 0.f, 0.f, 0.f};
    if(tid < 256){
      const int q4 = (tid & 63) >> 4, rr16 = tid & 15;
      const int jl = (tid >> 6) * 16 + rr16;
      #pragma unroll
      for(int kt = 8; kt < 16; ++kt){
        int k0 = kt * 32 + q4 * 8;
        v8s av = *(const v8s*)&AT[rr16][k0];
        v8s bv = *(const v8s*)&WT[jl][k0];
        acc = __builtin_amdgcn_mfma_f32_16x16x32_bf16(av, bv, acc, 0, 0, 0);
      }
    }

    // ---- scores: thread (sb=lane, q=wid): s = lane*8+j, a in [16q,16q+16) ----
    {
      float sc[8];
      #pragma unroll
      for(int j = 0; j < 8; ++j) sc[j] = 0.f;
      #pragma unroll
      for(int i = 0; i < 16; ++i){
        int a = wid * 16 + i;
        float dd = dpf[a], vv = vl[a];
        sc[0] += vv * ftanh(unlo(u[i].x) + dd);
        sc[1] += vv * ftanh(unhi(u[i].x) + dd);
        sc[2] += vv * ftanh(unlo(u[i].y) + dd);
        sc[3] += vv * ftanh(unhi(u[i].y) + dd);
        sc[4] += vv * ftanh(unlo(u[i].z) + dd);
        sc[5] += vv * ftanh(unhi(u[i].z) + dd);
        sc[6] += vv * ftanh(unlo(u[i].w) + dd);
        sc[7] += vv * ftanh(unhi(u[i].w) + dd);
      }
      #pragma unroll
      for(int j = 0; j < 8; ++j) scp[lane * 8 + j][wid] = sc[j];
    }
    __syncthreads();

    // ---- softmax over S (max-free: |score| <= ||v||_1 ~ 5) ----
    float wexp;
    {
      float s = 0.f;
      #pragma unroll
      for(int q = 0; q < 8; ++q) s += scp[tid][q];
      wexp = fexp2(s * LOG2E);
      float sw = wave_sum(wexp);
      if(lane == 0) red2[wid] = sw;
    }
    __syncthreads();
    {
      float L = red2[0];
      #pragma unroll
      for(int i = 1; i < 8; ++i) L += red2[i];
      attn_l[tid] = wexp * frcp(L);
    }
    __syncthreads();

    // ---- context: register double-buffered stream of encb ----
    {
      int e4 = tid & 31, g = tid >> 5;
      const uint4* ebg = eb + ((size_t)g * 32) * 32 + e4;
      const float* al = &attn_l[g * 32];
      uint4 ca[8], cbf[8];
      float a8[8] = {0.f, 0.f, 0.f, 0.f, 0.f, 0.f, 0.f, 0.f};
      #pragma unroll
      for(int i = 0; i < 8; ++i) ca[i] = ebg[i * 32];
      #pragma unroll
      for(int i = 0; i < 8; ++i) cbf[i] = ebg[(8 + i) * 32];
      #pragma unroll
      for(int i = 0; i < 8; ++i){
        float at = al[i];
        a8[0] += at * unlo(ca[i].x); a8[1] += at * unhi(ca[i].x);
        a8[2] += at * unlo(ca[i].y); a8[3] += at * unhi(ca[i].y);
        a8[4] += at * unlo(ca[i].z); a8[5] += at * unhi(ca[i].z);
        a8[6] += at * unlo(ca[i].w); a8[7] += at * unhi(ca[i].w);
      }
      #pragma unroll
      for(int i = 0; i < 8; ++i) ca[i] = ebg[(16 + i) * 32];
      #pragma unroll
      for(int i = 0; i < 8; ++i){
        float at = al[8 + i];
        a8[0] += at * unlo(cbf[i].x); a8[1] += at * unhi(cbf[i].x);
        a8[2] += at * unlo(cbf[i].y); a8[3] += at * unhi(cbf[i].y);
        a8[4] += at * unlo(cbf[i].z); a8[5] += at * unhi(cbf[i].z);
        a8[6] += at * unlo(cbf[i].w); a8[7] += at * unhi(cbf[i].w);
      }
      #pragma unroll
      for(int i = 0; i < 8; ++i) cbf[i] = ebg[(24 + i) * 32];
      #pragma unroll
      for(int i = 0; i < 8; ++i){
        float at = al[16 + i];
        a8[0] += at * unlo(ca[i].x); a8[1] += at * unhi(ca[i].x);
        a8[2] += at * unlo(ca[i].y); a8[3] += at * unhi(ca[i].y);
        a8[4] += at * unlo(ca[i].z); a8[5] += at * unhi(ca[i].z);
        a8[6] += at * unlo(ca[i].w); a8[7] += at * unhi(ca[i].w);
      }
      #pragma unroll
      for(int i = 0; i < 8; ++i){
        float at = al[24 + i];
        a8[0] += at * unlo(cbf[i].x); a8[1] += at * unhi(cbf[i].x);
        a8[2] += at * unlo(cbf[i].y); a8[3] += at * unhi(cbf[i].y);
        a8[4] += at * unlo(cbf[i].z); a8[5] += at * unhi(cbf[i].z);
        a8[6] += at * unlo(cbf[i].w); a8[7] += at * unhi(cbf[i].w);
      }
      #pragma unroll
      for(int j = 0; j < 8; ++j) ctxp[g][j][e4] = a8[j];   // conflict-free
    }
    __syncthreads();
    if(tid < 128){
      int e0 = 2 * tid, e1 = e0 + 1;
      float s0 = 0.f, s1 = 0.f;
      #pragma unroll
      for(int g2 = 0; g2 < 16; ++g2){
        s0 += ctxp[g2][e0 & 7][e0 >> 3];
        s1 += ctxp[g2][e1 & 7][e1 >> 3];
      }
      st32_c((uint32_t*)&xcatP[(size_t)b * 512 + 2 * tid], pack2(s0, s1));
    }
    __syncthreads();                 // drains vmcnt: ctx stores acked at L3
    if(tid == 0) flag_st(&flagA[b], (unsigned)(t + 1));
    out[12288 + (size_t)b * 24576 + t * 512 + tid] = attn_l[tid];  // off critical path

    // ---- B: wait attn(t) of all 16 batches; gates ctx-half + pointwise ----
    if(tid < 16){
      unsigned want = (unsigned)(t + 1);
      while(flag_ld(&flagA[m16 + tid]) < want) __builtin_amdgcn_s_sleep(1);
    }
    __syncthreads();
    {
      const uint64_t* csrc = (const uint64_t*)(xcatP + (size_t)m16 * 512);
      #pragma unroll
      for(int i = 0; i < 2; ++i){
        int flat = i * 512 + tid;          // 1024 = 16 rows x 64 u64 (ctx half)
        int r = flat >> 6, q = flat & 63;
        *(uint64_t*)&AT[r][q * 4] = ld64_c(csrc + (size_t)r * 128 + q);
      }
      if(tid < 16) predfL[tid] = ldf_c(&predf[m16 + tid]);
    }
    __syncthreads();
    if(tid < 256){
      const int q4 = (tid & 63) >> 4, rr16 = tid & 15;
      const int jl = (tid >> 6) * 16 + rr16;
      #pragma unroll
      for(int kt = 0; kt < 8; ++kt){
        int k0 = kt * 32 + q4 * 8;
        v8s av = *(const v8s*)&AT[rr16][k0];
        v8s bv = *(const v8s*)&WT[jl][k0];
        acc = __builtin_amdgcn_mfma_f32_16x16x32_bf16(av, bv, acc, 0, 0, 0);
      }
      float bias = biasL[jl], w0 = w0L[jl];
      int gate = jl & 3;
      #pragma unroll
      for(int r = 0; r < 4; ++r){
        int bl = q4 * 4 + r;
        float pre = acc[r] + bias + predfL[bl] * w0;
        gact[jl][bl] = (gate == 2) ? ftanh(pre) : fsig(pre);
      }
    }
    __syncthreads();
    if(tid < 256){
      int bl = tid >> 4, dl = tid & 15;
      float gi = gact[dl * 4 + 0][bl];
      float gf = gact[dl * 4 + 1][bl];
      float gg = gact[dl * 4 + 2][bl];
      float go = gact[dl * 4 + 3][bl];
      int bg = m16 + bl, dg = n * 16 + dl;
      float cn = gf * c_reg + gi * gg;
      c_reg = cn;
      float hn = go * ftanh(cn);
      st16_c(&xcatN[(size_t)bg * 512 + 256 + dg], (unsigned short)bf16r(hn));
      float pp = hn * WoutL[dl];
      #pragma unroll
      for(int o = 8; o; o >>= 1) pp += __shfl_xor(pp, o, 64);
      if(dl == 0) stf_c(&predp[n * 256 + bg], pp);
      // dp-partial fused: h of (bl,d) fetched via intra-wave shfl (no LDS/barrier)
      float a0[8] = {0, 0, 0, 0, 0, 0, 0, 0};
      #pragma unroll
      for(int d = 0; d < 16; ++d){
        float hv = __shfl(hn, (lane & 48) + d, 64);
        #pragma unroll
        for(int j = 0; j < 8; ++j) a0[j] += hv * WdecL[d][dl * 8 + j];
      }
      float* dst = &dpp[((size_t)bg * 16 + n) * 128 + dl * 8];
      #pragma unroll
      for(int j = 0; j < 4; ++j){
        uint64_t uu = (uint64_t)__float_as_uint(a0[2 * j]) |
                      ((uint64_t)__float_as_uint(a0[2 * j + 1]) << 32);
        st64_c((uint64_t*)(dst + 2 * j), uu);
      }
    }
    __syncthreads();                 // drains vmcnt: dpp/predp/h stores acked
    if(tid == 0) flag_st(&flagB[b], (unsigned)(t + 1));
  }

  // ---- finalize t=47 prediction ----
  if(tid < 16){
    while(flag_ld(&flagB[m16 + tid]) < 48u) __builtin_amdgcn_s_sleep(1);
  }
  __syncthreads();
  if(tid == 0){
    float pf = 0.f;
    #pragma unroll
    for(int nn = 0; nn < 16; ++nn) pf += ldf_c(&predp[nn * 256 + b]);
    out[b * 48 + 47] = pf + sB;
  }
}

extern "C" void kernel_launch(void* const* d_in, const int* in_sizes, int n_in,
                              void* d_out, int out_size, void* d_ws, size_t ws_size,
                              hipStream_t stream) {
  (void)in_sizes; (void)n_in; (void)out_size; (void)ws_size;
  const float* enc  = (const float*)d_in[0];
  const float* h0   = (const float*)d_in[1];
  const float* c0   = (const float*)d_in[2];
  const float* Wenc = (const float*)d_in[3];
  const float* Wdec = (const float*)d_in[4];
  const float* v    = (const float*)d_in[5];
  const float* Wih  = (const float*)d_in[6];
  const float* Whh  = (const float*)d_in[7];
  const float* bih  = (const float*)d_in[8];
  const float* bhh  = (const float*)d_in[9];
  const float* Wout = (const float*)d_in[10];
  const float* bout = (const float*)d_in[11];
  float* out = (float*)d_out;
  uint8_t* p = (uint8_t*)d_ws;

  uint32_t* encb = (uint32_t*)p;            p += 67108864ull;  // [256][512][128] u32 pairs
  unsigned short* ep = (unsigned short*)p;  p += 33554432ull;  // [256][128][512] bf16
  unsigned short* WmT = (unsigned short*)p; p += 1048576ull;   // [1024][512] bf16
  float* biasc  = (float*)p;                p += 4096ull;
  float* w0v    = (float*)p;                p += 4096ull;
  unsigned short* WencTh = (unsigned short*)p; p += 131072ull; // [128][256] bf16 hi
  unsigned short* WencTl = (unsigned short*)p; p += 131072ull; // [128][256] bf16 lo
  float* dpp    = (float*)p;                p += 2097152ull;   // [256][16][128] f32
  float* predp  = (float*)p;                p += 16384ull;     // [16][256] f32
  unsigned short* xcat2 = (unsigned short*)p; p += 524288ull;  // 2 x [256][512] bf16

  // flags/predf alias WencTh's space (dead after k_enc_proj; k_zero runs after it)
  unsigned* flagA = (unsigned*)WencTh;        // [256]
  unsigned* flagB = flagA + 256;              // [256]
  float*    predf = (float*)(flagA + 512);    // [256]

  k_pack<<<dim3(384), dim3(256), 0, stream>>>(Wih, Whh, bih, bhh, Wenc, WmT, biasc, w0v,
                                              WencTh, WencTl);
  k_enc_proj<<<dim3(1024), dim3(256), 0, stream>>>(enc, WencTh, WencTl, ep, encb);
  k_zero<<<dim3(1), dim3(512), 0, stream>>>(flagA);
  k_steps<<<dim3(256), dim3(512), 0, stream>>>(encb, ep, WmT, biasc, w0v, Wdec, Wout,
                                               h0, c0, v, bout, flagA, flagB, predf,
                                               dpp, predp, xcat2, out);
}

// Round 4
// 1240.567 us; speedup vs baseline: 3.1562x; 3.1562x over previous
//
#include <hip/hip_runtime.h>
#include <stdint.h>

// B=256, S=512, ENC=256, DEC=256, ATTN=128, H=48
#define LOG2E 1.4426950408889634f
#define SCOPE __HIP_MEMORY_SCOPE_AGENT

typedef short v8s __attribute__((ext_vector_type(8)));
typedef float v4f __attribute__((ext_vector_type(4)));

__device__ __forceinline__ uint32_t bf16r(float x){
  uint32_t u = __float_as_uint(x);
  return (u + 0x7fffu + ((u >> 16) & 1u)) >> 16;   // RNE round to bf16
}
__device__ __forceinline__ uint32_t pack2(float lo, float hi){
  return bf16r(lo) | (bf16r(hi) << 16);
}
__device__ __forceinline__ float unlo(uint32_t u){ return __uint_as_float(u << 16); }
__device__ __forceinline__ float unhi(uint32_t u){ return __uint_as_float(u & 0xffff0000u); }

__device__ __forceinline__ float fexp2(float x){ return __builtin_amdgcn_exp2f(x); }
__device__ __forceinline__ float frcp(float x){ return __builtin_amdgcn_rcpf(x); }
__device__ __forceinline__ float ftanh(float x){
  float e = fexp2(x * (2.0f * LOG2E));   // exp(2x)
  return 1.0f - 2.0f * frcp(e + 1.0f);
}
__device__ __forceinline__ float fsig(float x){
  return frcp(1.0f + fexp2(-x * LOG2E));
}
__device__ __forceinline__ float wave_sum(float x){
  #pragma unroll
  for(int o = 32; o; o >>= 1) x += __shfl_xor(x, o, 64);
  return x;
}

// Coherent (agent-scope, L3-serialized) access helpers.
__device__ __forceinline__ unsigned flag_ld(const unsigned* p){
  return __hip_atomic_load(p, __ATOMIC_RELAXED, SCOPE);
}
__device__ __forceinline__ void flag_st(unsigned* p, unsigned v){
  __hip_atomic_store(p, v, __ATOMIC_RELAXED, SCOPE);
}
__device__ __forceinline__ float ldf_c(const float* p){
  return __hip_atomic_load(p, __ATOMIC_RELAXED, SCOPE);
}
__device__ __forceinline__ void stf_c(float* p, float v){
  __hip_atomic_store(p, v, __ATOMIC_RELAXED, SCOPE);
}
__device__ __forceinline__ uint64_t ld64_c(const uint64_t* p){
  return __hip_atomic_load(p, __ATOMIC_RELAXED, SCOPE);
}
__device__ __forceinline__ void st64_c(uint64_t* p, uint64_t v){
  __hip_atomic_store(p, v, __ATOMIC_RELAXED, SCOPE);
}
__device__ __forceinline__ void st16_c(unsigned short* p, unsigned short v){
  __hip_atomic_store(p, v, __ATOMIC_RELAXED, SCOPE);
}

// Gate-row interleave: jg = n*64 + dl*4 + gate ; row = gate*256 + n*16 + dl
__device__ __forceinline__ int gate_row(int jg){
  return (jg & 3) * 256 + (jg >> 6) * 16 + ((jg >> 2) & 15);
}

// ---- P1: pack gate weights bf16 (interleaved rows) + WencT split hi/lo bf16 ----
__global__ __launch_bounds__(256) void k_pack(const float* __restrict__ W_ih,
                                              const float* __restrict__ W_hh,
                                              const float* __restrict__ b_ih,
                                              const float* __restrict__ b_hh,
                                              const float* __restrict__ W_enc,
                                              unsigned short* __restrict__ WmT,
                                              float* __restrict__ biasc,
                                              float* __restrict__ w0v,
                                              unsigned short* __restrict__ WencTh,
                                              unsigned short* __restrict__ WencTl){
  int gid = blockIdx.x * 256 + threadIdx.x;   // 98304
  if(gid < 65536){
    int jg = gid >> 6, k8 = gid & 63;
    int row = gate_row(jg);
    int k0 = k8 * 8;
    uint32_t p[4];
    #pragma unroll
    for(int mm = 0; mm < 4; ++mm){
      int ka = k0 + 2 * mm, kb = ka + 1;
      float lo = (ka < 256) ? W_ih[row * 257 + 1 + ka] : W_hh[row * 256 + (ka - 256)];
      float hi = (kb < 256) ? W_ih[row * 257 + 1 + kb] : W_hh[row * 256 + (kb - 256)];
      p[mm] = pack2(lo, hi);
    }
    *(uint4*)&WmT[(size_t)jg * 512 + k0] = make_uint4(p[0], p[1], p[2], p[3]);
    if(k8 == 0){
      biasc[jg] = b_ih[row] + b_hh[row];
      w0v[jg] = W_ih[row * 257];
    }
  } else {
    int g2 = gid - 65536;                    // 32768 = 256k x 128a
    int k = g2 >> 7, a = g2 & 127;
    float x = W_enc[k * 128 + a];
    uint32_t hb = bf16r(x);
    WencTh[a * 256 + k] = (unsigned short)hb;
    float hv = __uint_as_float(hb << 16);
    WencTl[a * 256 + k] = (unsigned short)bf16r(x - hv);
  }
}

// ---- P2: enc_proj via MFMA bf16 (split hi/lo) + encbT transposed bf16 emit ----
__global__ __launch_bounds__(256, 2) void k_enc_proj(const float* __restrict__ enc,
                                                     const unsigned short* __restrict__ WencTh,
                                                     const unsigned short* __restrict__ WencTl,
                                                     unsigned short* __restrict__ ep,
                                                     unsigned short* __restrict__ encbT){
  __shared__ unsigned short Ash[128][48];  // [s-local][k-chunk] hi
  __shared__ unsigned short Asl[128][48];  // lo
  __shared__ unsigned short Wth[128][48];  // [a][k-chunk] hi
  __shared__ unsigned short Wtl[128][48];  // lo
  const int tid = threadIdx.x;
  const int b = blockIdx.x >> 2, mt = blockIdx.x & 3;
  const int lane = tid & 63, w = tid >> 6;
  const int rr = lane & 15, quad = lane >> 4;

  v4f acc[2][8];
  #pragma unroll
  for(int g = 0; g < 2; ++g)
    #pragma unroll
    for(int nt = 0; nt < 8; ++nt) acc[g][nt] = (v4f){0.f, 0.f, 0.f, 0.f};

  const float* encBase = enc + ((size_t)(b * 512 + mt * 128)) * 256;

  for(int kt = 0; kt < 8; ++kt){
    __syncthreads();
    #pragma unroll
    for(int i = 0; i < 4; ++i){
      int flat = i * 256 + tid;              // 1024 = 128 rows x 8 float4
      int row = flat >> 3, c4 = flat & 7;
      float4 f = *(const float4*)(encBase + (size_t)row * 256 + kt * 32 + c4 * 4);
      uint32_t hx = bf16r(f.x), hy = bf16r(f.y), hz = bf16r(f.z), hw = bf16r(f.w);
      uint2 hp = make_uint2(hx | (hy << 16), hz | (hw << 16));
      float lx = f.x - __uint_as_float(hx << 16);
      float ly = f.y - __uint_as_float(hy << 16);
      float lz = f.z - __uint_as_float(hz << 16);
      float lw = f.w - __uint_as_float(hw << 16);
      uint2 lp = make_uint2(pack2(lx, ly), pack2(lz, lw));
      *(uint2*)&Ash[row][c4 * 4] = hp;
      *(uint2*)&Asl[row][c4 * 4] = lp;
    }
    #pragma unroll
    for(int i = 0; i < 2; ++i){
      int flat = i * 256 + tid;              // 512 = 128 a x 4 uint4
      int a = flat >> 2, q4 = flat & 3;
      *(uint4*)&Wth[a][q4 * 8] = *(const uint4*)(WencTh + (size_t)a * 256 + kt * 32 + q4 * 8);
      *(uint4*)&Wtl[a][q4 * 8] = *(const uint4*)(WencTl + (size_t)a * 256 + kt * 32 + q4 * 8);
    }
    __syncthreads();
    #pragma unroll
    for(int g = 0; g < 2; ++g){
      v8s ah = *(const v8s*)&Ash[32 * w + 16 * g + rr][quad * 8];
      v8s al = *(const v8s*)&Asl[32 * w + 16 * g + rr][quad * 8];
      #pragma unroll
      for(int nt = 0; nt < 8; ++nt){
        v8s bh = *(const v8s*)&Wth[nt * 16 + rr][quad * 8];
        v8s bl = *(const v8s*)&Wtl[nt * 16 + rr][quad * 8];
        acc[g][nt] = __builtin_amdgcn_mfma_f32_16x16x32_bf16(ah, bh, acc[g][nt], 0, 0, 0);
        acc[g][nt] = __builtin_amdgcn_mfma_f32_16x16x32_bf16(al, bh, acc[g][nt], 0, 0, 0);
        acc[g][nt] = __builtin_amdgcn_mfma_f32_16x16x32_bf16(ah, bl, acc[g][nt], 0, 0, 0);
      }
    }
    // encbT transpose-write: tile e=[kt*32,+32), s=[mt*128,+128) (reads Ash)
    {
      unsigned short* ebT = encbT + ((size_t)(b * 256 + kt * 32)) * 512 + mt * 128;
      #pragma unroll
      for(int i2 = 0; i2 < 2; ++i2){
        int flat = i2 * 256 + tid;           // 512 = 32 e x 16 s-chunks
        int e_loc = flat & 31, sc = flat >> 5;
        unsigned short tmp[8];
        #pragma unroll
        for(int i = 0; i < 8; ++i) tmp[i] = Ash[sc * 8 + i][e_loc];
        *(uint4*)&ebT[(size_t)e_loc * 512 + sc * 8] = *(uint4*)tmp;
      }
    }
  }
  #pragma unroll
  for(int g = 0; g < 2; ++g){
    int s0 = 128 * mt + 32 * w + 16 * g + quad * 4;
    #pragma unroll
    for(int nt = 0; nt < 8; ++nt){
      int a = nt * 16 + rr;
      uint2 pp = make_uint2(pack2(acc[g][nt][0], acc[g][nt][1]),
                            pack2(acc[g][nt][2], acc[g][nt][3]));
      *(uint2*)&ep[((size_t)b * 128 + a) * 512 + s0] = pp;
    }
  }
}

// ---- P3: reset flags (ws persists across harness iterations) ----
__global__ __launch_bounds__(512) void k_zero(unsigned* __restrict__ fl){
  fl[threadIdx.x] = 0u;   // flagA[256] | flagB[256]
}

// ---- Persistent fused decoder. Per step, block b: (A) attention for batch b
// with context via MFMA (attn hi/lo bf16 x encbT), gates h-half MFMA overlapped
// with scores; (B) gates ctx-half + LSTM pointwise for m-group slice n.
// Cross-block handoff via generation flags + agent-scope relaxed atomics.
__global__ __launch_bounds__(512, 2) void k_steps(
    const unsigned short* __restrict__ encbT, const unsigned short* __restrict__ ep,
    const unsigned short* __restrict__ WmT, const float* __restrict__ biasc,
    const float* __restrict__ w0v, const float* __restrict__ Wdec,
    const float* __restrict__ Wout, const float* __restrict__ h0,
    const float* __restrict__ c0, const float* __restrict__ v,
    const float* __restrict__ b_out, unsigned* __restrict__ flagA,
    unsigned* __restrict__ flagB, float* __restrict__ predf,
    float* __restrict__ dpp, float* __restrict__ predp,
    unsigned short* __restrict__ xcat2, float* __restrict__ out)
{
  __shared__ __align__(16) unsigned short WT[64][520];  // gate weights (persistent)
  __shared__ __align__(16) unsigned short AT[16][520];  // x rows: [0,256)=ctx [256,512)=h
  __shared__ float WdecL[16][128];                      // Wdec slice (persistent)
  __shared__ float gact[64][20];
  __shared__ float dpf[128];
  __shared__ float vl[128];
  __shared__ float scp[64][65];                         // [(s&7)*8+q][s>>3]
  __shared__ float red2[8];
  __shared__ float hf[256];
  __shared__ float dppart[4][128];
  __shared__ __align__(16) unsigned short abfh[512];    // attn bf16 hi
  __shared__ __align__(16) unsigned short abfl[512];    // attn bf16 lo
  __shared__ float biasL[64], w0L[64], WoutL[16], predfL[16];
  __shared__ float sB;

  const int tid = threadIdx.x, b = blockIdx.x;
  const int lane = tid & 63, wid = tid >> 6;
  const int quad = lane >> 4, rr = lane & 15;
  const int m16 = (b >> 4) << 4;     // first batch of our m-group
  const int n = b & 15;              // our gates n-slice

  // ---- one-time staging ----
  {
    const uint4* src = (const uint4*)(WmT + (size_t)(n * 64) * 512);
    #pragma unroll
    for(int i = 0; i < 8; ++i){
      int flat = i * 512 + tid;            // 4096 = 64 rows x 64 uint4
      int r = flat >> 6, q = flat & 63;
      *(uint4*)&WT[r][q * 8] = src[r * 64 + q];
    }
    const float4* wsrc = (const float4*)(Wdec + (size_t)(n * 16) * 128);
    int r2 = tid >> 5, q2 = tid & 31;      // 512 = 16 rows x 32 float4
    *(float4*)&WdecL[r2][q2 * 4] = wsrc[r2 * 32 + q2];
    if(tid < 64){ biasL[tid] = biasc[n * 64 + tid]; w0L[tid] = w0v[n * 64 + tid]; }
    if(tid < 16) WoutL[tid] = Wout[n * 16 + tid];
    if(tid < 128) vl[tid] = v[tid];
    if(tid == 0){ sB = b_out[0]; stf_c(&predf[b], 0.f); }
    // stage AT h-half from h0 directly (t=0 gates input; no cross-block dep)
    #pragma unroll
    for(int i = 0; i < 8; ++i){
      int flat = i * 512 + tid;            // 4096 = 16 r x 256 c
      int r = flat >> 8, c = flat & 255;
      AT[r][256 + c] = (unsigned short)bf16r(h0[(size_t)(m16 + r) * 256 + c]);
    }
  }
  float c_reg = 0.f;
  if(tid < 256){
    int bl = tid >> 4, dl = tid & 15;
    c_reg = c0[(size_t)(m16 + bl) * 256 + n * 16 + dl];
    hf[tid] = h0[(size_t)b * 256 + tid];
  }
  __syncthreads();
  // dpf(t=0) = h0 @ Wdec (f32)
  {
    int a = tid & 127, p = tid >> 7;
    float s = 0.f;
    const float* wd = Wdec + (size_t)(p * 64) * 128 + a;
    #pragma unroll 8
    for(int d = 0; d < 64; ++d) s += hf[p * 64 + d] * wd[(size_t)d * 128];
    dppart[p][a] = s;
  }
  __syncthreads();
  if(tid < 128) dpf[tid] = dppart[0][tid] + dppart[1][tid] + dppart[2][tid] + dppart[3][tid];
  __syncthreads();

  const uint4* ep4 = (const uint4*)(ep + (size_t)b * 65536);

  #pragma unroll 1
  for(int t = 0; t < 48; ++t){
    unsigned short* xcatP = xcat2 + (size_t)(t & 1) * 131072;        // x_t
    unsigned short* xcatN = xcat2 + (size_t)((t + 1) & 1) * 131072;  // h_{t+1} dest

    // ---- A: wait gates(t-1); restage AT h-half; fold dpp/predp ----
    if(t > 0){
      if(tid < 16){
        unsigned want = (unsigned)t;
        while(flag_ld(&flagB[m16 + tid]) < want) __builtin_amdgcn_s_sleep(1);
      }
      __syncthreads();
      {
        const uint64_t* hsrc = (const uint64_t*)(xcatP + (size_t)m16 * 512);
        #pragma unroll
        for(int i = 0; i < 2; ++i){
          int flat = i * 512 + tid;        // 1024 = 16 rows x 64 u64 (h half)
          int r = flat >> 6, q = flat & 63;
          *(uint64_t*)&AT[r][256 + q * 4] = ld64_c(hsrc + (size_t)r * 128 + 64 + q);
        }
      }
      if(tid < 128){
        float s = 0.f;
        #pragma unroll
        for(int nn = 0; nn < 16; ++nn) s += ldf_c(&dpp[((size_t)b * 16 + nn) * 128 + tid]);
        dpf[tid] = s;
      } else if(tid == 128){
        float pf = 0.f;
        #pragma unroll
        for(int nn = 0; nn < 16; ++nn) pf += ldf_c(&predp[nn * 256 + b]);
        pf += sB;
        out[b * 48 + (t - 1)] = pf;
        stf_c(&predf[b], pf);
      }
      __syncthreads();
    }

    // ---- ep loads in flight; gates h-half MFMA (matrix pipe) under scores ----
    uint4 u[16];
    #pragma unroll
    for(int i = 0; i < 16; ++i) u[i] = ep4[(wid * 16 + i) * 64 + lane];

    v4f acc = {0.f, 0.f, 0.f, 0.f};
    if(tid < 256){
      const int jl = (tid >> 6) * 16 + rr;
      #pragma unroll
      for(int kt = 8; kt < 16; ++kt){
        int k0 = kt * 32 + quad * 8;
        v8s av = *(const v8s*)&AT[rr][k0];
        v8s bv = *(const v8s*)&WT[jl][k0];
        acc = __builtin_amdgcn_mfma_f32_16x16x32_bf16(av, bv, acc, 0, 0, 0);
      }
    }

    // ---- scores: thread (lane, q=wid): s = lane*8+j, a in [16q,16q+16) ----
    {
      float sc[8];
      #pragma unroll
      for(int j = 0; j < 8; ++j) sc[j] = 0.f;
      #pragma unroll
      for(int i = 0; i < 16; ++i){
        int a = wid * 16 + i;
        float dd = dpf[a], vv = vl[a];
        sc[0] += vv * ftanh(unlo(u[i].x) + dd);
        sc[1] += vv * ftanh(unhi(u[i].x) + dd);
        sc[2] += vv * ftanh(unlo(u[i].y) + dd);
        sc[3] += vv * ftanh(unhi(u[i].y) + dd);
        sc[4] += vv * ftanh(unlo(u[i].z) + dd);
        sc[5] += vv * ftanh(unhi(u[i].z) + dd);
        sc[6] += vv * ftanh(unlo(u[i].w) + dd);
        sc[7] += vv * ftanh(unhi(u[i].w) + dd);
      }
      #pragma unroll
      for(int j = 0; j < 8; ++j) scp[j * 8 + wid][lane] = sc[j];   // conflict-free
    }
    __syncthreads();

    // ---- softmax over S (max-free: |score| <= ||v||_1 ~ 5) ----
    float wexp;
    {
      float s = 0.f;
      #pragma unroll
      for(int q = 0; q < 8; ++q) s += scp[(tid & 7) * 8 + q][tid >> 3];  // 2-way
      wexp = fexp2(s * LOG2E);
      float sw = wave_sum(wexp);
      if(lane == 0) red2[wid] = sw;
    }
    __syncthreads();
    {
      float L = red2[0];
      #pragma unroll
      for(int i = 1; i < 8; ++i) L += red2[i];
      float aw = wexp * frcp(L);
      uint32_t ah = bf16r(aw);
      abfh[tid] = (unsigned short)ah;
      abfl[tid] = (unsigned short)bf16r(aw - __uint_as_float(ah << 16));
      out[12288 + (size_t)b * 24576 + t * 512 + tid] = aw;
    }
    __syncthreads();

    // ---- context via MFMA: ctx = (attn_h + attn_l) . encbT^T, fp32 acc ----
    {
      const unsigned short* eT =
          encbT + ((size_t)(b * 256) + wid * 32 + rr) * 512 + quad * 8;
      v4f ca = {0.f, 0.f, 0.f, 0.f}, cb = {0.f, 0.f, 0.f, 0.f};
      #pragma unroll 4
      for(int kt = 0; kt < 16; ++kt){
        int k0 = kt * 32;
        v8s avh = *(const v8s*)&abfh[k0 + quad * 8];
        v8s avl = *(const v8s*)&abfl[k0 + quad * 8];
        v8s bv0 = *(const v8s*)(eT + k0);
        v8s bv1 = *(const v8s*)(eT + 16 * 512 + k0);
        ca = __builtin_amdgcn_mfma_f32_16x16x32_bf16(avh, bv0, ca, 0, 0, 0);
        ca = __builtin_amdgcn_mfma_f32_16x16x32_bf16(avl, bv0, ca, 0, 0, 0);
        cb = __builtin_amdgcn_mfma_f32_16x16x32_bf16(avh, bv1, cb, 0, 0, 0);
        cb = __builtin_amdgcn_mfma_f32_16x16x32_bf16(avl, bv1, cb, 0, 0, 0);
      }
      if(quad == 0){   // all D-rows identical (broadcast A); row 0 suffices
        st16_c(&xcatP[(size_t)b * 512 + wid * 32 + rr], (unsigned short)bf16r(ca[0]));
        st16_c(&xcatP[(size_t)b * 512 + wid * 32 + 16 + rr], (unsigned short)bf16r(cb[0]));
      }
    }
    __syncthreads();                 // drains vmcnt: ctx stores acked at L3
    if(tid == 0) flag_st(&flagA[b], (unsigned)(t + 1));

    // ---- B: wait attn(t) of all 16 batches; gates ctx-half + pointwise ----
    if(tid < 16){
      unsigned want = (unsigned)(t + 1);
      while(flag_ld(&flagA[m16 + tid]) < want) __builtin_amdgcn_s_sleep(1);
    }
    __syncthreads();
    {
      const uint64_t* csrc = (const uint64_t*)(xcatP + (size_t)m16 * 512);
      #pragma unroll
      for(int i = 0; i < 2; ++i){
        int flat = i * 512 + tid;          // 1024 = 16 rows x 64 u64 (ctx half)
        int r = flat >> 6, q = flat & 63;
        *(uint64_t*)&AT[r][q * 4] = ld64_c(csrc + (size_t)r * 128 + q);
      }
      if(tid < 16) predfL[tid] = ldf_c(&predf[m16 + tid]);
    }
    __syncthreads();
    if(tid < 256){
      const int jl = (tid >> 6) * 16 + rr;
      #pragma unroll
      for(int kt = 0; kt < 8; ++kt){
        int k0 = kt * 32 + quad * 8;
        v8s av = *(const v8s*)&AT[rr][k0];
        v8s bv = *(const v8s*)&WT[jl][k0];
        acc = __builtin_amdgcn_mfma_f32_16x16x32_bf16(av, bv, acc, 0, 0, 0);
      }
      float bias = biasL[jl], w0 = w0L[jl];
      int gate = jl & 3;
      #pragma unroll
      for(int r = 0; r < 4; ++r){
        int bl = quad * 4 + r;
        float pre = acc[r] + bias + predfL[bl] * w0;
        gact[jl][bl] = (gate == 2) ? ftanh(pre) : fsig(pre);
      }
    }
    __syncthreads();
    if(tid < 256){
      int bl = tid >> 4, dl = tid & 15;
      float gi = gact[dl * 4 + 0][bl];
      float gf = gact[dl * 4 + 1][bl];
      float gg = gact[dl * 4 + 2][bl];
      float go = gact[dl * 4 + 3][bl];
      int bg = m16 + bl, dg = n * 16 + dl;
      float cn = gf * c_reg + gi * gg;
      c_reg = cn;
      float hn = go * ftanh(cn);
      st16_c(&xcatN[(size_t)bg * 512 + 256 + dg], (unsigned short)bf16r(hn));
      float pp = hn * WoutL[dl];
      #pragma unroll
      for(int o = 8; o; o >>= 1) pp += __shfl_xor(pp, o, 64);
      if(dl == 0) stf_c(&predp[n * 256 + bg], pp);
      // dp-partial fused: h of (bl,d) via intra-wave shfl (no LDS/barrier)
      float a0[8] = {0, 0, 0, 0, 0, 0, 0, 0};
      #pragma unroll
      for(int d = 0; d < 16; ++d){
        float hv = __shfl(hn, (lane & 48) + d, 64);
        #pragma unroll
        for(int j = 0; j < 8; ++j) a0[j] += hv * WdecL[d][dl * 8 + j];
      }
      float* dst = &dpp[((size_t)bg * 16 + n) * 128 + dl * 8];
      #pragma unroll
      for(int j = 0; j < 4; ++j){
        uint64_t uu = (uint64_t)__float_as_uint(a0[2 * j]) |
                      ((uint64_t)__float_as_uint(a0[2 * j + 1]) << 32);
        st64_c((uint64_t*)(dst + 2 * j), uu);
      }
    }
    __syncthreads();                 // drains vmcnt: dpp/predp/h stores acked
    if(tid == 0) flag_st(&flagB[b], (unsigned)(t + 1));
  }

  // ---- finalize t=47 prediction ----
  if(tid < 16){
    while(flag_ld(&flagB[m16 + tid]) < 48u) __builtin_amdgcn_s_sleep(1);
  }
  __syncthreads();
  if(tid == 0){
    float pf = 0.f;
    #pragma unroll
    for(int nn = 0; nn < 16; ++nn) pf += ldf_c(&predp[nn * 256 + b]);
    out[b * 48 + 47] = pf + sB;
  }
}

extern "C" void kernel_launch(void* const* d_in, const int* in_sizes, int n_in,
                              void* d_out, int out_size, void* d_ws, size_t ws_size,
                              hipStream_t stream) {
  (void)in_sizes; (void)n_in; (void)out_size; (void)ws_size;
  const float* enc  = (const float*)d_in[0];
  const float* h0   = (const float*)d_in[1];
  const float* c0   = (const float*)d_in[2];
  const float* Wenc = (const float*)d_in[3];
  const float* Wdec = (const float*)d_in[4];
  const float* v    = (const float*)d_in[5];
  const float* Wih  = (const float*)d_in[6];
  const float* Whh  = (const float*)d_in[7];
  const float* bih  = (const float*)d_in[8];
  const float* bhh  = (const float*)d_in[9];
  const float* Wout = (const float*)d_in[10];
  const float* bout = (const float*)d_in[11];
  float* out = (float*)d_out;
  uint8_t* p = (uint8_t*)d_ws;

  unsigned short* encbT = (unsigned short*)p; p += 67108864ull; // [256][256][512] bf16
  unsigned short* ep = (unsigned short*)p;  p += 33554432ull;   // [256][128][512] bf16
  unsigned short* WmT = (unsigned short*)p; p += 1048576ull;    // [1024][512] bf16
  float* biasc  = (float*)p;                p += 4096ull;
  float* w0v    = (float*)p;                p += 4096ull;
  unsigned short* WencTh = (unsigned short*)p; p += 131072ull;  // [128][256] bf16 hi
  unsigned short* WencTl = (unsigned short*)p; p += 131072ull;  // [128][256] bf16 lo
  float* dpp    = (float*)p;                p += 2097152ull;    // [256][16][128] f32
  float* predp  = (float*)p;                p += 16384ull;      // [16][256] f32
  unsigned short* xcat2 = (unsigned short*)p; p += 524288ull;   // 2 x [256][512] bf16

  // flags/predf alias WencTh's space (dead after k_enc_proj; k_zero runs after it)
  unsigned* flagA = (unsigned*)WencTh;        // [256]
  unsigned* flagB = flagA + 256;              // [256]
  float*    predf = (float*)(flagA + 512);    // [256]

  k_pack<<<dim3(384), dim3(256), 0, stream>>>(Wih, Whh, bih, bhh, Wenc, WmT, biasc, w0v,
                                              WencTh, WencTl);
  k_enc_proj<<<dim3(1024), dim3(256), 0, stream>>>(enc, WencTh, WencTl, ep, encbT);
  k_zero<<<dim3(1), dim3(512), 0, stream>>>(flagA);
  k_steps<<<dim3(256), dim3(512), 0, stream>>>(encbT, ep, WmT, biasc, w0v, Wdec, Wout,
                                               h0, c0, v, bout, flagA, flagB, predf,
                                               dpp, predp, xcat2, out);
}